// Round 1
// baseline (506.898 us; speedup 1.0000x reference)
//
#include <hip/hip_runtime.h>
#include <hip/hip_bf16.h>
#include <cstdint>

typedef __bf16 bf16;
typedef bf16 bf16x8 __attribute__((ext_vector_type(8)));
typedef bf16 bf16x4 __attribute__((ext_vector_type(4)));
typedef float f32x4 __attribute__((ext_vector_type(4)));

__device__ __forceinline__ void gl_lds16(const bf16* g, bf16* l) {
    __builtin_amdgcn_global_load_lds((const __attribute__((address_space(1))) void*)g,
                                     (__attribute__((address_space(3))) void*)l, 16, 0, 0);
}

// ---------------- fp32 -> bf16 flat convert ----------------
__global__ void k_cvt_bf16(const float* __restrict__ in, bf16* __restrict__ out, int n4) {
    int i = blockIdx.x * blockDim.x + threadIdx.x;
    if (i < n4) {
        f32x4 v = *(const f32x4*)(in + (size_t)i * 4);
        bf16x4 o = { (bf16)v[0], (bf16)v[1], (bf16)v[2], (bf16)v[3] };
        *(bf16x4*)(out + (size_t)i * 4) = o;
    }
}

// ---------------- (K,N) fp32 -> (N,K) bf16 transpose ----------------
__global__ void k_transpose_cvt(const float* __restrict__ in, bf16* __restrict__ out, int K, int Nn) {
    __shared__ float tile[32][33];
    int k0 = blockIdx.x * 32, n0 = blockIdx.y * 32;
    int tx = threadIdx.x, ty = threadIdx.y;   // 32 x 8
#pragma unroll
    for (int i = 0; i < 4; i++) {
        int k = k0 + ty + i * 8;
        tile[ty + i * 8][tx] = in[(size_t)k * Nn + n0 + tx];
    }
    __syncthreads();
#pragma unroll
    for (int i = 0; i < 4; i++) {
        int n = n0 + ty + i * 8;
        out[(size_t)n * K + k0 + tx] = (bf16)tile[tx][ty + i * 8];
    }
}

// ---------------- RoPE cos/sin tables: (B*N, 104) ----------------
__global__ void k_rope_tables(const int* __restrict__ coords, float* __restrict__ cosT, float* __restrict__ sinT) {
    int bn = blockIdx.x * blockDim.x + threadIdx.x;
    if (bn >= 4096) return;
    int c0 = coords[bn * 3 + 0], c1 = coords[bn * 3 + 1], c2 = coords[bn * 3 + 2];
    float* co = cosT + (size_t)bn * 104;
    float* si = sinT + (size_t)bn * 104;
    const float LN1E4 = 9.210340371976184f; // ln(10000)
    for (int d = 0; d < 104; d++) {
        int j, dp, c;
        if (d < 34)      { int dd = d;      j = dd < 17 ? dd : dd - 17; dp = 34; c = c0; }
        else if (d < 68) { int dd = d - 34; j = dd < 17 ? dd : dd - 17; dp = 34; c = c1; }
        else             { int dd = d - 68; j = dd < 18 ? dd : dd - 18; dp = 36; c = c2; }
        float inv = expf(-2.0f * (float)j / (float)dp * LN1E4);
        float a = (float)c * inv;
        co[d] = cosf(a);
        si[d] = sinf(a);
    }
}

// ---------------- 128x128 bf16 MFMA GEMM, B^T input, bias epilogue ----------------
template <bool OUT_BF16>
__global__ __launch_bounds__(256) void k_gemm(const bf16* __restrict__ A, const bf16* __restrict__ BT,
                                              const float* __restrict__ bias, void* __restrict__ Cout,
                                              int M, int Nn, int K) {
    __shared__ __align__(16) bf16 aT[128 * 32];
    __shared__ __align__(16) bf16 bT[128 * 32];
    int t = threadIdx.x;
    int m0 = blockIdx.y * 128, n0 = blockIdx.x * 128;
    int w = t >> 6, l = t & 63, quad = l >> 4, lc = l & 15;
    int wm = (w >> 1) * 64, wn = (w & 1) * 64;
    f32x4 acc[4][4] = {};
    for (int k0 = 0; k0 < K; k0 += 32) {
#pragma unroll
        for (int it = 0; it < 2; it++) {
            int c = it * 256 + t;
            int r = c >> 2, kc = c & 3;
            gl_lds16(A  + (size_t)(m0 + r) * K + k0 + kc * 8, aT + c * 8);
            gl_lds16(BT + (size_t)(n0 + r) * K + k0 + kc * 8, bT + c * 8);
        }
        __syncthreads();
        bf16x8 af[4], bfr[4];
#pragma unroll
        for (int i = 0; i < 4; i++) {
            af[i]  = *(const bf16x8*)(aT + (wm + i * 16 + lc) * 32 + quad * 8);
            bfr[i] = *(const bf16x8*)(bT + (wn + i * 16 + lc) * 32 + quad * 8);
        }
#pragma unroll
        for (int i = 0; i < 4; i++)
#pragma unroll
            for (int j = 0; j < 4; j++)
                acc[i][j] = __builtin_amdgcn_mfma_f32_16x16x32_bf16(af[i], bfr[j], acc[i][j], 0, 0, 0);
        __syncthreads();
    }
#pragma unroll
    for (int i = 0; i < 4; i++)
#pragma unroll
        for (int j = 0; j < 4; j++) {
            int col = n0 + wn + j * 16 + lc;
            float bv = bias[col];
#pragma unroll
            for (int r = 0; r < 4; r++) {
                int row = m0 + wm + i * 16 + quad * 4 + r;
                float v = acc[i][j][r] + bv;
                if (OUT_BF16) ((bf16*)Cout)[(size_t)row * Nn + col] = (bf16)v;
                else          ((float*)Cout)[(size_t)row * Nn + col] = v;
            }
        }
}

// ---------------- RoPE apply + scatter q,k into (B,H,N,128) bf16 padded ----------------
__global__ void k_rope_scatter(const bf16* __restrict__ qkv, const float* __restrict__ cosT,
                               const float* __restrict__ sinT, bf16* __restrict__ qp, bf16* __restrict__ kp) {
    int idx = blockIdx.x * blockDim.x + threadIdx.x;  // 65536 = B*N*H
    if (idx >= 65536) return;
    int h = idx & 15, n = (idx >> 4) & 2047, b = idx >> 15;
    int bn = b * 2048 + n;
    const bf16* qrow = qkv + (size_t)bn * 4992 + h * 104;
    const bf16* krow = qrow + 1664;
    const float* co = cosT + (size_t)bn * 104;
    const float* si = sinT + (size_t)bn * 104;
    int bh = b * 16 + h;
    bf16* qo = qp + ((size_t)bh * 2048 + n) * 128;
    bf16* ko = kp + ((size_t)bh * 2048 + n) * 128;
    const float scale = 0.09805806756909202f; // 104^-0.5 folded into q
#pragma unroll
    for (int cc = 0; cc < 13; cc++) {
        int d = cc * 4;
        bf16x4 q1 = *(const bf16x4*)(qrow + d);
        bf16x4 q2 = *(const bf16x4*)(qrow + d + 52);
        bf16x4 k1 = *(const bf16x4*)(krow + d);
        bf16x4 k2 = *(const bf16x4*)(krow + d + 52);
        f32x4 c1 = *(const f32x4*)(co + d);
        f32x4 c2 = *(const f32x4*)(co + d + 52);
        f32x4 s1 = *(const f32x4*)(si + d);
        f32x4 s2 = *(const f32x4*)(si + d + 52);
        bf16x4 o1, o2, p1, p2;
#pragma unroll
        for (int i = 0; i < 4; i++) {
            float fq1 = (float)q1[i], fq2 = (float)q2[i];
            float fk1 = (float)k1[i], fk2 = (float)k2[i];
            o1[i] = (bf16)((fq1 * c1[i] - fq2 * s1[i]) * scale);
            o2[i] = (bf16)((fq2 * c2[i] + fq1 * s2[i]) * scale);
            p1[i] = (bf16)(fk1 * c1[i] - fk2 * s1[i]);
            p2[i] = (bf16)(fk2 * c2[i] + fk1 * s2[i]);
        }
        *(bf16x4*)(qo + d) = o1;
        *(bf16x4*)(qo + d + 52) = o2;
        *(bf16x4*)(ko + d) = p1;
        *(bf16x4*)(ko + d + 52) = p2;
    }
    bf16x8 z = {};
    *(bf16x8*)(qo + 104) = z; *(bf16x8*)(qo + 112) = z; *(bf16x8*)(qo + 120) = z;
    *(bf16x8*)(ko + 104) = z; *(bf16x8*)(ko + 112) = z; *(bf16x8*)(ko + 120) = z;
}

// ---------------- V transpose: qkv v-part -> (B,H,128,N) bf16, pad rows zeroed ----------------
__global__ void k_v_transpose(const bf16* __restrict__ qkv, bf16* __restrict__ vt) {
    __shared__ bf16 tile[32][33];
    int bh = blockIdx.x; int b = bh >> 4, h = bh & 15;
    int n0 = blockIdx.y * 32, d0 = blockIdx.z * 32;
    int tx = threadIdx.x, ty = threadIdx.y;
#pragma unroll
    for (int i = 0; i < 4; i++) {
        int n = n0 + ty + i * 8; int d = d0 + tx;
        bf16 v = (bf16)0.0f;
        if (d < 104) v = qkv[(size_t)(b * 2048 + n) * 4992 + 3328 + h * 104 + d];
        tile[ty + i * 8][tx] = v;
    }
    __syncthreads();
    bf16* vto = vt + (size_t)bh * 128 * 2048;
#pragma unroll
    for (int i = 0; i < 4; i++) {
        int d = d0 + ty + i * 8; int n = n0 + tx;
        vto[(size_t)d * 2048 + n] = tile[tx][ty + i * 8];
    }
}

// ---------------- Flash attention: 128 q-rows/block, 64-key tiles, online softmax ----------------
__global__ __launch_bounds__(256) void k_attn(const bf16* __restrict__ qp, const bf16* __restrict__ kp,
                                              const bf16* __restrict__ vt, bf16* __restrict__ out) {
    __shared__ __align__(16) bf16 kT[64 * 128];   // swizzled: slot = key*16 + (dc ^ (key&15))
    __shared__ __align__(16) bf16 vT[128 * 64];   // swizzled: slot = d*8 + (kc ^ (d&7))
    __shared__ __align__(16) bf16 pS[4][16 * 72]; // per-wave P scratch, padded stride 72
    int t = threadIdx.x;
    int bh = blockIdx.x, qt = blockIdx.y;
    int w = t >> 6, l = t & 63, quad = l >> 4, lc = l & 15;
    const bf16* Q  = qp + (size_t)bh * 2048 * 128;
    const bf16* Kb = kp + (size_t)bh * 2048 * 128;
    const bf16* Vb = vt + (size_t)bh * 128 * 2048;
    int q0 = qt * 128;
    int wq = q0 + w * 32;
    bf16x8 qf[2][4];
#pragma unroll
    for (int mt = 0; mt < 2; mt++)
#pragma unroll
        for (int kc = 0; kc < 4; kc++)
            qf[mt][kc] = *(const bf16x8*)(Q + (size_t)(wq + mt * 16 + lc) * 128 + kc * 32 + quad * 8);
    f32x4 accO[2][7] = {};
    f32x4 mRun[2], lRun[2];
#pragma unroll
    for (int mt = 0; mt < 2; mt++)
#pragma unroll
        for (int r = 0; r < 4; r++) { mRun[mt][r] = -1e30f; lRun[mt][r] = 0.f; }

    for (int kv0 = 0; kv0 < 2048; kv0 += 64) {
#pragma unroll
        for (int it = 0; it < 4; it++) {
            int s = it * 256 + t;
            int key = s >> 4, dcs = s & 15;
            int dc = dcs ^ (key & 15);
            gl_lds16(Kb + (size_t)(kv0 + key) * 128 + dc * 8, kT + s * 8);
            int d = s >> 3, kcs = s & 7;
            int kc = kcs ^ (d & 7);
            gl_lds16(Vb + (size_t)d * 2048 + kv0 + kc * 8, vT + s * 8);
        }
        __syncthreads();
#pragma unroll
        for (int mt = 0; mt < 2; mt++) {
            f32x4 sf[4] = {};
#pragma unroll
            for (int ns = 0; ns < 4; ns++) {
                int key = ns * 16 + lc;
#pragma unroll
                for (int kc = 0; kc < 4; kc++) {
                    int dc = kc * 4 + quad;
                    int slot = key * 16 + (dc ^ (key & 15));
                    bf16x8 kf = *(const bf16x8*)(kT + slot * 8);
                    sf[ns] = __builtin_amdgcn_mfma_f32_16x16x32_bf16(qf[mt][kc], kf, sf[ns], 0, 0, 0);
                }
            }
            // row max over 4 subtiles then across the 16-lane col group
            f32x4 tmax = sf[0];
#pragma unroll
            for (int ns = 1; ns < 4; ns++)
#pragma unroll
                for (int r = 0; r < 4; r++) tmax[r] = fmaxf(tmax[r], sf[ns][r]);
#pragma unroll
            for (int off = 1; off < 16; off <<= 1)
#pragma unroll
                for (int r = 0; r < 4; r++) {
                    float tv = tmax[r];
                    tmax[r] = fmaxf(tv, __shfl_xor(tv, off));
                }
            f32x4 mNew, alpha;
#pragma unroll
            for (int r = 0; r < 4; r++) {
                mNew[r] = fmaxf(mRun[mt][r], tmax[r]);
                alpha[r] = __expf(mRun[mt][r] - mNew[r]);
                mRun[mt][r] = mNew[r];
            }
            f32x4 psum = {};
#pragma unroll
            for (int ns = 0; ns < 4; ns++)
#pragma unroll
                for (int r = 0; r < 4; r++) {
                    float p = __expf(sf[ns][r] - mNew[r]);
                    psum[r] += p;
                    pS[w][(quad * 4 + r) * 72 + ns * 16 + lc] = (bf16)p;
                }
#pragma unroll
            for (int off = 1; off < 16; off <<= 1)
#pragma unroll
                for (int r = 0; r < 4; r++) {
                    float pv = psum[r];
                    psum[r] = pv + __shfl_xor(pv, off);
                }
#pragma unroll
            for (int r = 0; r < 4; r++) lRun[mt][r] = lRun[mt][r] * alpha[r] + psum[r];
#pragma unroll
            for (int ns = 0; ns < 7; ns++)
#pragma unroll
                for (int r = 0; r < 4; r++) accO[mt][ns][r] *= alpha[r];
            asm volatile("s_waitcnt lgkmcnt(0)" ::: "memory");
            bf16x8 pf[2];
#pragma unroll
            for (int ks = 0; ks < 2; ks++)
                pf[ks] = *(const bf16x8*)(&pS[w][lc * 72 + ks * 32 + quad * 8]);
#pragma unroll
            for (int ks = 0; ks < 2; ks++)
#pragma unroll
                for (int ns = 0; ns < 7; ns++) {
                    int d = ns * 16 + lc;
                    int kc = ks * 4 + quad;
                    int slot = d * 8 + (kc ^ (d & 7));
                    bf16x8 vf = *(const bf16x8*)(vT + slot * 8);
                    accO[mt][ns] = __builtin_amdgcn_mfma_f32_16x16x32_bf16(pf[ks], vf, accO[mt][ns], 0, 0, 0);
                }
        }
        __syncthreads();
    }
    int b = bh >> 4, h = bh & 15;
#pragma unroll
    for (int mt = 0; mt < 2; mt++)
#pragma unroll
        for (int ns = 0; ns < 7; ns++) {
            int dcol = ns * 16 + lc;
            if (dcol >= 104) continue;
#pragma unroll
            for (int r = 0; r < 4; r++) {
                int row = wq + mt * 16 + quad * 4 + r;
                float v = accO[mt][ns][r] / lRun[mt][r];
                out[((size_t)(b * 2048 + row)) * 1664 + h * 104 + dcol] = (bf16)v;
            }
        }
}

extern "C" void kernel_launch(void* const* d_in, const int* in_sizes, int n_in,
                              void* d_out, int out_size, void* d_ws, size_t ws_size,
                              hipStream_t stream) {
    const float* x      = (const float*)d_in[0];
    const int*   coords = (const int*)d_in[1];
    const float* qkv_w  = (const float*)d_in[2];
    const float* qkv_b  = (const float*)d_in[3];
    const float* proj_w = (const float*)d_in[4];
    const float* proj_b = (const float*)d_in[5];
    float* out = (float*)d_out;
    uint8_t* ws = (uint8_t*)d_ws;

    constexpr size_t SZ_XB    = 4096ull * 1664 * 2;   // 13,631,488
    constexpr size_t SZ_WQKV  = 4992ull * 1664 * 2;   // 16,613,376
    constexpr size_t SZ_WPROJ = 1664ull * 1664 * 2;   //  5,537,792
    constexpr size_t SZ_QKV   = 4096ull * 4992 * 2;   // 40,894,464
    constexpr size_t SZ_QPAD  = 32ull * 2048 * 128 * 2; // 16,777,216
    constexpr size_t SZ_CS    = 4096ull * 104 * 4;    //  1,703,936

    size_t o_xb    = 0;
    size_t o_wqkv  = o_xb + SZ_XB;
    size_t o_wproj = o_wqkv + SZ_WQKV;
    size_t o_qkv   = o_wproj + SZ_WPROJ;
    size_t o_kpad  = o_qkv + SZ_QKV;
    size_t o_vt    = o_kpad + SZ_QPAD;
    size_t o_cos   = o_vt + SZ_QPAD;
    size_t o_sin   = o_cos + SZ_CS;
    // aliases (safe: strictly ordered producer/consumer on one stream):
    size_t o_qpad  = 0;        // reuses xb+wqkvT region after qkv GEMM
    size_t o_attn  = o_qkv;    // reuses qkv region after rope_scatter + v_transpose

    bf16* xb     = (bf16*)(ws + o_xb);
    bf16* wqkvT  = (bf16*)(ws + o_wqkv);
    bf16* wprojT = (bf16*)(ws + o_wproj);
    bf16* qkvb   = (bf16*)(ws + o_qkv);
    bf16* qpad   = (bf16*)(ws + o_qpad);
    bf16* kpad   = (bf16*)(ws + o_kpad);
    bf16* vtpad  = (bf16*)(ws + o_vt);
    float* cosT  = (float*)(ws + o_cos);
    float* sinT  = (float*)(ws + o_sin);
    bf16* attno  = (bf16*)(ws + o_attn);

    k_cvt_bf16<<<6656, 256, 0, stream>>>(x, xb, 1703936);
    k_transpose_cvt<<<dim3(52, 156), dim3(32, 8), 0, stream>>>(qkv_w, wqkvT, 1664, 4992);
    k_transpose_cvt<<<dim3(52, 52), dim3(32, 8), 0, stream>>>(proj_w, wprojT, 1664, 1664);
    k_rope_tables<<<16, 256, 0, stream>>>(coords, cosT, sinT);
    k_gemm<true><<<dim3(39, 32), 256, 0, stream>>>(xb, wqkvT, qkv_b, (void*)qkvb, 4096, 4992, 1664);
    k_rope_scatter<<<256, 256, 0, stream>>>(qkvb, cosT, sinT, qpad, kpad);
    k_v_transpose<<<dim3(32, 64, 4), dim3(32, 8), 0, stream>>>(qkvb, vtpad);
    k_attn<<<dim3(32, 16), 256, 0, stream>>>(qpad, kpad, vtpad, attno);
    k_gemm<false><<<dim3(13, 32), 256, 0, stream>>>(attno, wprojT, proj_b, (void*)out, 4096, 1664, 1664);
}